// Round 9
// baseline (67.202 us; speedup 1.0000x reference)
//
#include <hip/hip_runtime.h>

// out[b,c,d,h,w] = in[b,0,d, clamp(h+dy,0,H-1), clamp(w+dx,0,W-1)]
// (dy,dx): c0:(-1,-1) c1:(0,0) c2:(+1,+1) c3:(+1,-1) c4:(-1,+1)
// B=2, D=48, H=256, W=512 f32.
//
// R9 = champion R4 + two read-side changes:
//  (1) nontemporal LOADS for the window: input (50MB) is L3-resident; keep
//      it out of L2 so the full 4MiB/XCD serves write-combining for the
//      252MB nt-store stream. Seam loads stay cached.
//  (2) XCD-aware swizzle (1536 = 8*192, bijective): h-adjacent blocks of
//      the same (b,d) slice land on the same XCD -> halo-row re-reads stay
//      local.
// Store structure identical to R4 (53.5us): HB=8, half-row waves, 1KB
// contiguous per store instruction, channel-major, nt stores.

typedef float f32x4 __attribute__((ext_vector_type(4)));

constexpr int D = 48, H = 256, W = 512;
constexpr int W4 = W / 4;     // 128 float4 slots: two waves cover one row
constexpr int HB = 8;         // output rows per thread
constexpr int WIN = HB + 2;

__device__ __forceinline__ void nt_store(float* p, float a, float b, float c, float d) {
    f32x4 v = {a, b, c, d};
    __builtin_nontemporal_store(v, reinterpret_cast<f32x4*>(p));
}

__global__ __launch_bounds__(256) void prop_kernel(
    const float* __restrict__ in, float* __restrict__ out) {
    const int w4   = threadIdx.x & (W4 - 1);   // 0..127
    const int hgrp = threadIdx.x >> 7;         // 0..1
    const int lane = threadIdx.x & 63;

    // XCD swizzle: nwg=1536 (%8==0) -> 192 consecutive logical blocks/XCD.
    int lb = (blockIdx.x & 7) * 192 + (blockIdx.x >> 3);
    const int h16 = lb & 15;                   // 16 h-blocks of 16 rows
    lb >>= 4;
    const int d = lb % D;
    const int b = lb / D;

    const int h0 = h16 * (2 * HB) + hgrp * HB; // first output row
    const int w0 = w4 * 4;

    const float* base = in + (b * D + d) * (H * W);

    // Window [h0-1 .. h0+HB] clamped; nt loads (L2 no-allocate, L3 serves
    // re-reads). L/R halo via shuffle; seam lanes use cached scalar loads.
    f32x4 v[WIN];
    float L[WIN], R[WIN];
    #pragma unroll
    for (int i = 0; i < WIN; ++i) {
        int r = h0 - 1 + i;
        r = r < 0 ? 0 : (r > H - 1 ? H - 1 : r);
        const float* row = base + r * W;
        f32x4 t = __builtin_nontemporal_load(reinterpret_cast<const f32x4*>(row + w0));
        float l  = __shfl_up(t.w, 1);          // lane i-1's w0+3 == our w0-1
        float rr = __shfl_down(t.x, 1);        // lane i+1's w0   == our w0+4
        if (w4 == 0)          l  = t.x;        // clamp at W edge
        else if (lane == 0)   l  = row[w0 - 1];    // wave seam (cached load)
        if (w4 == W4 - 1)     rr = t.w;        // clamp at W edge
        else if (lane == 63)  rr = row[w0 + 4];    // wave seam (cached load)
        v[i] = t; L[i] = l; R[i] = rr;
    }

    const int planeDHW = D * H * W;            // 6,291,456
    float* o0 = out + ((b * 5) * D + d) * (H * W) + h0 * W + w0;

    // Channel-major stores: per channel, HB rows of 1KB-contiguous wave
    // bursts (R4-proven structure).
    #pragma unroll
    for (int j = 0; j < HB; ++j) {  // c0: row h-1, w-1..w+2
        nt_store(o0 + j * W, L[j], v[j].x, v[j].y, v[j].z);
    }
    #pragma unroll
    for (int j = 0; j < HB; ++j) {  // c1: row h, w..w+3
        nt_store(o0 + planeDHW + j * W, v[j+1].x, v[j+1].y, v[j+1].z, v[j+1].w);
    }
    #pragma unroll
    for (int j = 0; j < HB; ++j) {  // c2: row h+1, w+1..w+4
        nt_store(o0 + 2 * planeDHW + j * W, v[j+2].y, v[j+2].z, v[j+2].w, R[j+2]);
    }
    #pragma unroll
    for (int j = 0; j < HB; ++j) {  // c3: row h+1, w-1..w+2
        nt_store(o0 + 3 * planeDHW + j * W, L[j+2], v[j+2].x, v[j+2].y, v[j+2].z);
    }
    #pragma unroll
    for (int j = 0; j < HB; ++j) {  // c4: row h-1, w+1..w+4
        nt_store(o0 + 4 * planeDHW + j * W, v[j].y, v[j].z, v[j].w, R[j]);
    }
}

extern "C" void kernel_launch(void* const* d_in, const int* in_sizes, int n_in,
                              void* d_out, int out_size, void* d_ws, size_t ws_size,
                              hipStream_t stream) {
    const float* in = (const float*)d_in[0];
    float* out = (float*)d_out;

    // grid: B * D * (H / 16) = 2 * 48 * 16 = 1536 blocks, exact cover
    const int grid = 2 * D * (H / (2 * HB));
    prop_kernel<<<grid, 256, 0, stream>>>(in, out);
}

// Round 10
// 53.716 us; speedup vs baseline: 1.2511x; 1.2511x over previous
//
#include <hip/hip_runtime.h>

// out[b,c,d,h,w] = in[b,0,d, clamp(h+dy,0,H-1), clamp(w+dx,0,W-1)]
// (dy,dx): c0:(-1,-1) c1:(0,0) c2:(+1,+1) c3:(+1,-1) c4:(-1,+1)
// B=2, D=48, H=256, W=512 f32.
//
// R10 = R4 verbatim (champion, 53.5us, ~5.9 TB/s effective mixed BW).
// A/B history: plain stores -65.2us (R6), full-row lanes 166us (R7, 1.7x
// write amp), perfect-burst half-row 55.3us (R8), nt-loads+XCD-swizzle
// 67.2us (R9). All deviations regressed; 53-57us cluster across three
// structurally distinct designs = practical mixed read/write DRAM ceiling
// for this 1:5 read:write 5-stream pattern.
//
// Structure: HB=8 rows/thread (10 window-row float4 loads -> 40 float4 nt
// stores, 1.25x read redundancy), w-halos via intra-wave shuffle (seam
// lanes take a cached scalar load), channel-major store order (1KB
// contiguous wave bursts), nontemporal stores (keeps 252MB write stream
// from thrashing L2/L3, input stays cache-resident for halo re-reads).

typedef float f32x4 __attribute__((ext_vector_type(4)));

constexpr int D = 48, H = 256, W = 512;
constexpr int W4 = W / 4;     // 128: two waves cover one full row
constexpr int HB = 8;         // output rows per thread

__device__ __forceinline__ void nt_store4(float* p, float a, float b, float c, float d) {
    f32x4 v = {a, b, c, d};
    __builtin_nontemporal_store(v, reinterpret_cast<f32x4*>(p));
}

__global__ __launch_bounds__(256) void prop_kernel(
    const float* __restrict__ in, float* __restrict__ out) {
    const int w4   = threadIdx.x & (W4 - 1);   // 0..127
    const int hgrp = threadIdx.x >> 7;         // 0..1 (two h-groups per block)
    const int lane = threadIdx.x & 63;

    int blk = blockIdx.x;
    const int h16 = blk & 15;                  // H / (2*HB) = 16 h-blocks
    blk >>= 4;
    const int d = blk % D;
    const int b = blk / D;

    const int h0 = h16 * (2 * HB) + hgrp * HB; // first output row
    const int w0 = w4 * 4;

    const float* base = in + (b * D + d) * (H * W);

    // Load (HB+2)-row window [h0-1 .. h0+HB] (clamped); L/R halo via shuffle.
    float4 v[HB + 2];
    float  L[HB + 2], R[HB + 2];
    #pragma unroll
    for (int i = 0; i < HB + 2; ++i) {
        int r = h0 - 1 + i;
        r = r < 0 ? 0 : (r > H - 1 ? H - 1 : r);
        const float* row = base + r * W;
        float4 t = *reinterpret_cast<const float4*>(row + w0);
        float l  = __shfl_up(t.w, 1);          // lane i-1's w0+3 == our w0-1
        float rr = __shfl_down(t.x, 1);        // lane i+1's w0   == our w0+4
        if (w4 == 0)          l  = t.x;        // clamp at W edge
        else if (lane == 0)   l  = row[w0 - 1];    // wave seam fallback
        if (w4 == W4 - 1)     rr = t.w;        // clamp at W edge
        else if (lane == 63)  rr = row[w0 + 4];    // wave seam fallback
        v[i] = t; L[i] = l; R[i] = rr;
    }

    const int planeDHW = D * H * W;            // 6,291,456
    float* o0 = out + ((b * 5) * D + d) * (H * W) + h0 * W + w0;

    // Channel-major stores: per channel, HB consecutive rows (contiguous
    // 1KB/wave lines) before switching streams.
    #pragma unroll
    for (int j = 0; j < HB; ++j) {  // c0: row h-1, w-1..w+2
        nt_store4(o0 + j * W, L[j], v[j].x, v[j].y, v[j].z);
    }
    #pragma unroll
    for (int j = 0; j < HB; ++j) {  // c1: row h, w..w+3
        nt_store4(o0 + planeDHW + j * W, v[j+1].x, v[j+1].y, v[j+1].z, v[j+1].w);
    }
    #pragma unroll
    for (int j = 0; j < HB; ++j) {  // c2: row h+1, w+1..w+4
        nt_store4(o0 + 2 * planeDHW + j * W, v[j+2].y, v[j+2].z, v[j+2].w, R[j+2]);
    }
    #pragma unroll
    for (int j = 0; j < HB; ++j) {  // c3: row h+1, w-1..w+2
        nt_store4(o0 + 3 * planeDHW + j * W, L[j+2], v[j+2].x, v[j+2].y, v[j+2].z);
    }
    #pragma unroll
    for (int j = 0; j < HB; ++j) {  // c4: row h-1, w+1..w+4
        nt_store4(o0 + 4 * planeDHW + j * W, v[j].y, v[j].z, v[j].w, R[j]);
    }
}

extern "C" void kernel_launch(void* const* d_in, const int* in_sizes, int n_in,
                              void* d_out, int out_size, void* d_ws, size_t ws_size,
                              hipStream_t stream) {
    const float* in = (const float*)d_in[0];
    float* out = (float*)d_out;

    // grid: B * D * (H / 16) = 2 * 48 * 16 = 1536 blocks, exact cover
    const int grid = 2 * D * (H / (2 * HB));
    prop_kernel<<<grid, 256, 0, stream>>>(in, out);
}